// Round 10
// baseline (28.912 us; speedup 1.0000x reference)
//
#include <hip/hip_runtime.h>

#define B_ 2
#define H_ 352
#define W_ 1216
#define HW_ (H_ * W_)      // 428032
#define K_ 9
#define TW 64              // tile width
#define TH 4               // tile height
#define SOFF 8             // halo margin
#define SR (TH + 2 * SOFF) // 20 staged rows
#define SC (TW + 2 * SOFF) // 80 staged cols
#define NBX (W_ / TW)      // 19
#define NBY (H_ / TH)      // 88
#define NTILE (B_ * NBX * NBY) // 3344
#define TPB 4              // tiles per (persistent) block
#define NPB (NTILE / TPB)  // 836 blocks x 256 threads
#define NV4 (SR * (SC / 4))    // 400 float4 halo elements

typedef float v4 __attribute__((ext_vector_type(4)));

struct Ctx { int b, oy, ox, y, x, p; };

__device__ __forceinline__ Ctx mkctx(int tile, int tx, int ty) {
    Ctx c;
    c.b = tile / (NBX * NBY);
    const int r  = tile - c.b * (NBX * NBY);
    const int by = r / NBX;
    const int bx = r - by * NBX;
    c.oy = by * TH - SOFF;
    c.ox = bx * TW - SOFF;
    c.y  = by * TH + ty;
    c.x  = bx * TW + tx;
    c.p  = c.y * W_ + c.x;
    return c;
}

// issue the 27 per-pixel stream loads (27 regs; latency hidden by caller)
__device__ __forceinline__ void ld_streams(const float* __restrict__ weight,
                                           const float* __restrict__ offset,
                                           const Ctx& c,
                                           float* ody, float* odx, float* wg) {
    const float* ob = offset + (size_t)c.b * 18 * HW_ + c.p;
    const float* wb = weight + (size_t)c.b * 9 * HW_ + c.p;
#pragma unroll
    for (int k = 0; k < K_; ++k) {
        ody[k] = ob[(2 * k) * HW_];
        odx[k] = ob[(2 * k + 1) * HW_];
    }
#pragma unroll
    for (int k = 0; k < K_; ++k) wg[k] = wb[k * HW_];
}

// T14 split: issue halo loads into regs (early) ...
__device__ __forceinline__ void halo_load(const float* __restrict__ depth,
                                          const Ctx& c, int tid, v4& h0, v4& h1) {
    const float* dpt = depth + c.b * HW_;
    {
        const int r  = tid / (SC / 4);
        const int c4 = (tid - r * (SC / 4)) * 4;
        const int gy = c.oy + r, gx = c.ox + c4;
        h0 = (v4)0.f;
        if ((unsigned)gy < (unsigned)H_ && (unsigned)gx < (unsigned)W_)
            h0 = *reinterpret_cast<const v4*>(dpt + gy * W_ + gx);
    }
    h1 = (v4)0.f;
    if (tid < NV4 - 256) {
        const int i  = tid + 256;
        const int r  = i / (SC / 4);
        const int c4 = (i - r * (SC / 4)) * 4;
        const int gy = c.oy + r, gx = c.ox + c4;
        if ((unsigned)gy < (unsigned)H_ && (unsigned)gx < (unsigned)W_)
            h1 = *reinterpret_cast<const v4*>(dpt + gy * W_ + gx);
    }
}

// ... and write them to LDS (late, after compute)
__device__ __forceinline__ void halo_write(float* sm, int tid, const v4 h0, const v4 h1) {
    {
        const int r  = tid / (SC / 4);
        const int c4 = (tid - r * (SC / 4)) * 4;
        *reinterpret_cast<v4*>(sm + r * SC + c4) = h0;
    }
    if (tid < NV4 - 256) {
        const int i  = tid + 256;
        const int r  = i / (SC / 4);
        const int c4 = (i - r * (SC / 4)) * 4;
        *reinterpret_cast<v4*>(sm + r * SC + c4) = h1;
    }
}

__device__ __forceinline__ void compute_tile(const float* __restrict__ sm,
                                             const float* __restrict__ depth,
                                             const Ctx& c, int tx, int ty,
                                             const float* ody, const float* odx,
                                             const float* wg_in, const float* wt,
                                             float bv, float* __restrict__ out) {
    const float* dpt = depth + c.b * HW_;
    float cf[K_];
    float m = 0.f;
#pragma unroll
    for (int k = 0; k < K_; ++k) m += wg_in[k];
    m *= (1.f / 9.f);
#pragma unroll
    for (int k = 0; k < K_; ++k) cf[k] = (wg_in[k] - m) * wt[k];

    const float dval = sm[(ty + SOFF) * SC + (tx + SOFF)];

    float acc = 0.f;
#pragma unroll
    for (int k = 0; k < K_; ++k) {
        const float py = (float)(c.y + (k / 3) - 1) + ody[k];
        const float px = (float)(c.x + (k % 3) - 1) + odx[k];
        const float y0f = floorf(py);
        const float x0f = floorf(px);
        const float fy = py - y0f;
        const float fx = px - x0f;
        const int yi0 = (int)y0f, xi0 = (int)x0f;

        const int ly = yi0 - c.oy;         // need [0, SR-2]
        const int lx = xi0 - c.ox;         // need [0, SC-2]
        float v00, v01, v10, v11;
        if (__builtin_expect((unsigned)ly <= (SR - 2) && (unsigned)lx <= (SC - 2), 1)) {
            const float* s = sm + ly * SC + lx;
            v00 = s[0];
            v01 = s[1];
            v10 = s[SC];
            v11 = s[SC + 1];
        } else {
            const int yi1 = yi0 + 1, xi1 = xi0 + 1;
            const bool vy0 = (unsigned)yi0 < (unsigned)H_;
            const bool vy1 = (unsigned)yi1 < (unsigned)H_;
            const bool vx0 = (unsigned)xi0 < (unsigned)W_;
            const bool vx1 = (unsigned)xi1 < (unsigned)W_;
            const int r0 = yi0 * W_;
            const int r1 = r0 + W_;
            v00 = (vy0 && vx0) ? dpt[r0 + xi0] : 0.f;
            v01 = (vy0 && vx1) ? dpt[r0 + xi1] : 0.f;
            v10 = (vy1 && vx0) ? dpt[r1 + xi0] : 0.f;
            v11 = (vy1 && vx1) ? dpt[r1 + xi1] : 0.f;
        }

        const float a   = fmaf(fx, v01 - v00, v00);
        const float cc  = fmaf(fx, v11 - v10, v10);
        const float val = fmaf(fy, cc - a, a);
        acc = fmaf(cf[k], val, acc);
    }

    out[c.b * HW_ + c.p] = acc + bv + dval;
}

__global__ __launch_bounds__(256, 4) void dcn_post_kernel(
    const float* __restrict__ depth,
    const float* __restrict__ weight,
    const float* __restrict__ offset,
    const float* __restrict__ wtap,
    const float* __restrict__ bias,
    float* __restrict__ out)
{
    __shared__ float smA[SR * SC];   // 6400 B
    __shared__ float smB[SR * SC];   // 6400 B

    const int tid = threadIdx.x;
    const int tx  = tid & (TW - 1);
    const int ty  = tid >> 6;
    const int t0  = blockIdx.x * TPB;

    float wt[K_];
#pragma unroll
    for (int k = 0; k < K_; ++k) wt[k] = wtap[k];
    const float bv = bias[0];

    float odyA[K_], odxA[K_], wgA[K_];
    float odyB[K_], odxB[K_], wgB[K_];
    v4 h0, h1;

    // ---- prologue: tile 0 ----
    Ctx cA = mkctx(t0 + 0, tx, ty);
    ld_streams(weight, offset, cA, odyA, odxA, wgA);
    halo_load(depth, cA, tid, h0, h1);
    halo_write(smA, tid, h0, h1);
    __syncthreads();

    // ---- phase 1: issue tile1, compute tile0 ----
    Ctx cB = mkctx(t0 + 1, tx, ty);
    ld_streams(weight, offset, cB, odyB, odxB, wgB);
    halo_load(depth, cB, tid, h0, h1);
    compute_tile(smA, depth, cA, tx, ty, odyA, odxA, wgA, wt, bv, out);
    halo_write(smB, tid, h0, h1);
    __syncthreads();

    // ---- phase 2: issue tile2, compute tile1 ----
    cA = mkctx(t0 + 2, tx, ty);
    ld_streams(weight, offset, cA, odyA, odxA, wgA);
    halo_load(depth, cA, tid, h0, h1);
    compute_tile(smB, depth, cB, tx, ty, odyB, odxB, wgB, wt, bv, out);
    halo_write(smA, tid, h0, h1);
    __syncthreads();

    // ---- phase 3: issue tile3, compute tile2 ----
    cB = mkctx(t0 + 3, tx, ty);
    ld_streams(weight, offset, cB, odyB, odxB, wgB);
    halo_load(depth, cB, tid, h0, h1);
    compute_tile(smA, depth, cA, tx, ty, odyA, odxA, wgA, wt, bv, out);
    halo_write(smB, tid, h0, h1);
    __syncthreads();

    // ---- epilogue: compute tile3 ----
    compute_tile(smB, depth, cB, tx, ty, odyB, odxB, wgB, wt, bv, out);
}

extern "C" void kernel_launch(void* const* d_in, const int* in_sizes, int n_in,
                              void* d_out, int out_size, void* d_ws, size_t ws_size,
                              hipStream_t stream) {
    const float* depth  = (const float*)d_in[0];
    const float* weight = (const float*)d_in[1];
    const float* offset = (const float*)d_in[2];
    const float* wtap   = (const float*)d_in[3];
    const float* bias   = (const float*)d_in[4];
    float* out = (float*)d_out;

    dim3 grid(NPB), block(256);
    hipLaunchKernelGGL(dcn_post_kernel, grid, block, 0, stream,
                       depth, weight, offset, wtap, bias, out);
}

// Round 11
// 24.387 us; speedup vs baseline: 1.1855x; 1.1855x over previous
//
#include <hip/hip_runtime.h>

#define B_ 2
#define H_ 352
#define W_ 1216
#define HW_ (H_ * W_)      // 428032
#define K_ 9
#define TW 64              // tile width (pixels)
#define TH 8               // tile height
#define SOFF 8             // halo margin (16B-aligned halo base)
#define SR (TH + 2 * SOFF) // 24 staged rows
#define SC (TW + 2 * SOFF) // 80 staged cols
#define NBX (W_ / TW)      // 19
#define NBY (H_ / TH)      // 44
#define NBLK (B_ * NBX * NBY)  // 1672 blocks x 512 threads
#define NV4 (SR * (SC / 4))    // 480 float4 stage elements

typedef float v4 __attribute__((ext_vector_type(4)));

__global__ __launch_bounds__(512) void dcn_post_kernel(
    const float* __restrict__ depth,
    const float* __restrict__ weight,
    const float* __restrict__ offset,
    const float* __restrict__ wtap,
    const float* __restrict__ bias,
    float* __restrict__ out)
{
    __shared__ float sm[SR * SC];   // 7680 B

    const int bid = blockIdx.x;
    const int b   = bid / (NBX * NBY);
    const int r2  = bid - b * (NBX * NBY);
    const int by  = r2 / NBX;
    const int bx  = r2 - by * NBX;
    const int tid = threadIdx.x;
    const int tx  = tid & (TW - 1);    // 0..63
    const int ty  = tid >> 6;          // 0..7

    const int y  = by * TH + ty;
    const int x  = bx * TW + tx;
    const int oy = by * TH - SOFF;
    const int ox = bx * TW - SOFF;     // multiple of 4 -> float4 staging aligned
    const int p  = y * W_ + x;

    const float* __restrict__ dpt = depth + b * HW_;

    // ---- ISSUE ORDER MATTERS (in-order vmcnt):
    // 1) halo float4 (so ds_write waits only on it, leaving streams in flight)
    v4 hv = 0.f;
    int hr = 0, hc4 = 0;
    const bool hact = (tid < NV4);
    if (hact) {
        hr  = tid / (SC / 4);
        hc4 = (tid - hr * (SC / 4)) * 4;
        const int gy = oy + hr;
        const int gx = ox + hc4;       // multiple of 4; fully in or out
        if ((unsigned)gy < (unsigned)H_ && (unsigned)gx < (unsigned)W_)
            hv = *reinterpret_cast<const v4*>(dpt + gy * W_ + gx);
    }

    // 2) modulation weights (consumed first after barrier)
    const float* wbase = weight + (size_t)b * K_ * HW_ + p;
    float wg[K_];
#pragma unroll
    for (int k = 0; k < K_; ++k) wg[k] = wbase[k * HW_];

    // 3) offsets (consumed per-tap; staged vmcnt waits let taps start early)
    const float* obase = offset + (size_t)b * 2 * K_ * HW_ + p;
    float ody[K_], odx[K_];
#pragma unroll
    for (int k = 0; k < K_; ++k) {
        ody[k] = obase[(2 * k) * HW_];
        odx[k] = obase[(2 * k + 1) * HW_];
    }

    // uniform params (scalar loads)
    float wt[K_];
#pragma unroll
    for (int k = 0; k < K_; ++k) wt[k] = wtap[k];
    const float bv = bias[0];

    // ---- halo ds_write (compiler waits vmcnt for hv only; streams stay in flight)
    if (hact)
        *reinterpret_cast<v4*>(sm + hr * SC + hc4) = hv;

    // ---- barrier WITHOUT the vmcnt(0) drain: only LDS writes must be visible.
    // Stream loads land in registers; no cross-wave visibility needed.
    asm volatile("s_waitcnt lgkmcnt(0)\n\ts_barrier" ::: "memory");

    // weight zero-mean + fold tap weight (needs wg only -> runs at vmcnt(18))
    float m = 0.f;
#pragma unroll
    for (int k = 0; k < K_; ++k) m += wg[k];
    m *= (1.f / 9.f);
    float cf[K_];
#pragma unroll
    for (int k = 0; k < K_; ++k) cf[k] = (wg[k] - m) * wt[k];

    const float dval = sm[(ty + SOFF) * SC + (tx + SOFF)];

    float acc = 0.f;
#pragma unroll
    for (int k = 0; k < K_; ++k) {
        const float py = (float)(y + (k / 3) - 1) + ody[k];
        const float px = (float)(x + (k % 3) - 1) + odx[k];
        const float y0f = floorf(py);
        const float x0f = floorf(px);
        const float fy = py - y0f;
        const float fx = px - x0f;
        const int yi0 = (int)y0f, xi0 = (int)x0f;

        const int ly = yi0 - oy;           // need [0, SR-2]
        const int lx = xi0 - ox;           // need [0, SC-2]
        float v00, v01, v10, v11;
        if (__builtin_expect((unsigned)ly <= (SR - 2) && (unsigned)lx <= (SC - 2), 1)) {
            const float* s = sm + ly * SC + lx;
            v00 = s[0];
            v01 = s[1];
            v10 = s[SC];
            v11 = s[SC + 1];
        } else {
            // ultra-rare fallback (|offset| > ~7): zero-padded global gather
            const int yi1 = yi0 + 1, xi1 = xi0 + 1;
            const bool vy0 = (unsigned)yi0 < (unsigned)H_;
            const bool vy1 = (unsigned)yi1 < (unsigned)H_;
            const bool vx0 = (unsigned)xi0 < (unsigned)W_;
            const bool vx1 = (unsigned)xi1 < (unsigned)W_;
            const int r0 = yi0 * W_;
            const int r1 = r0 + W_;
            v00 = (vy0 && vx0) ? dpt[r0 + xi0] : 0.f;
            v01 = (vy0 && vx1) ? dpt[r0 + xi1] : 0.f;
            v10 = (vy1 && vx0) ? dpt[r1 + xi0] : 0.f;
            v11 = (vy1 && vx1) ? dpt[r1 + xi1] : 0.f;
        }

        const float gy = 1.f - fy, gx = 1.f - fx;
        const float val = v00 * gy * gx + v01 * gy * fx
                        + v10 * fy * gx + v11 * fy * fx;
        acc = fmaf(cf[k], val, acc);
    }

    out[b * HW_ + p] = acc + bv + dval;
}

extern "C" void kernel_launch(void* const* d_in, const int* in_sizes, int n_in,
                              void* d_out, int out_size, void* d_ws, size_t ws_size,
                              hipStream_t stream) {
    const float* depth  = (const float*)d_in[0];
    const float* weight = (const float*)d_in[1];
    const float* offset = (const float*)d_in[2];
    const float* wtap   = (const float*)d_in[3];
    const float* bias   = (const float*)d_in[4];
    float* out = (float*)d_out;

    dim3 grid(NBLK), block(512);
    hipLaunchKernelGGL(dcn_post_kernel, grid, block, 0, stream,
                       depth, weight, offset, wtap, bias, out);
}